// Round 2
// baseline (1002.172 us; speedup 1.0000x reference)
//
#include <hip/hip_runtime.h>

#define B_ 4
#define C_ 256
#define H_ 128
#define W_ 128
#define HEADS_ 4
#define DH_ 64
#define L_ 2048                    // pooled sequence length 16*128 = 128*16
#define NPIX_ ((long)B_*C_*H_*W_)  // 16,777,216

// ---------------- pool: x (B,C,128,128) -> xh (B,C,16,128), xw (B,C,128,16) --
// xp layout: [2][B*C][L]  (branch 0 = H-pooled, branch 1 = W-pooled)
__global__ __launch_bounds__(256) void pool_kernel(const float* __restrict__ x,
                                                   float* __restrict__ xp) {
  int part = blockIdx.x & 1;          // half-plane (64 rows)
  int bc   = blockIdx.x >> 1;
  const float* px = x + (long)bc * (H_*W_) + (long)part * 64 * W_;
  __shared__ float pl[64 * W_];       // 32 KiB
  for (int i = threadIdx.x; i < 64*W_; i += 256) pl[i] = px[i];
  __syncthreads();
  const float inv = 0.125f;
  // H-pooled: outputs hh in [part*8, part*8+8), 8*128 = 1024 outputs
  float* xh = xp + (long)bc * L_ + (long)part * 8 * W_;
  for (int i = threadIdx.x; i < 8*W_; i += 256) {
    int hh = i >> 7, w = i & 127;
    float s = 0.f;
    #pragma unroll
    for (int p = 0; p < 8; ++p) s += pl[(hh*8+p)*W_ + w];
    xh[i] = s * inv;
  }
  // W-pooled: rows h in [part*64, part*64+64), 64*16 = 1024 outputs
  float* xw = xp + (long)(B_*C_ + bc) * L_ + (long)part * 64 * 16;
  for (int i = threadIdx.x; i < 64*16; i += 256) {
    int h = i >> 4, ww = i & 15;
    float s = 0.f;
    #pragma unroll
    for (int p = 0; p < 8; ++p) s += pl[h*W_ + ww*8 + p];
    xw[i] = s * inv;
  }
}

// ---------------- generic tiled GEMM with bias: Out[z] = A(MxK) * X[z](KxN) + b
__global__ __launch_bounds__(256) void gemm_bias_kernel(
    const float* __restrict__ A, const float* __restrict__ X,
    const float* __restrict__ bias, float* __restrict__ Out,
    int M, int N, int K, long xStride, long oStride) {
  const float* Xb = X + (long)blockIdx.z * xStride;
  float* Ob = Out + (long)blockIdx.z * oStride;
  int m0 = blockIdx.y * 64, n0 = blockIdx.x * 64;
  __shared__ float As[32][68];
  __shared__ float Xs[32][68];
  int tid = threadIdx.x;
  int ti = tid >> 4, tj = tid & 15;
  float acc[4][4] = {{0.f}};
  for (int k0 = 0; k0 < K; k0 += 32) {
    for (int idx = tid; idx < 64*32; idx += 256) {
      int o = idx >> 5, kk = idx & 31;
      As[kk][o] = A[(long)(m0+o)*K + k0 + kk];
    }
    for (int idx = tid; idx < 32*64; idx += 256) {
      int kk = idx >> 6, j = idx & 63;
      Xs[kk][j] = Xb[(long)(k0+kk)*N + n0 + j];
    }
    __syncthreads();
    #pragma unroll 8
    for (int kk = 0; kk < 32; ++kk) {
      float4 a4 = *(const float4*)&As[kk][ti*4];
      float4 b4 = *(const float4*)&Xs[kk][tj*4];
      float av[4] = {a4.x, a4.y, a4.z, a4.w};
      float bv[4] = {b4.x, b4.y, b4.z, b4.w};
      #pragma unroll
      for (int r = 0; r < 4; ++r)
        #pragma unroll
        for (int s = 0; s < 4; ++s) acc[r][s] += av[r]*bv[s];
    }
    __syncthreads();
  }
  #pragma unroll
  for (int r = 0; r < 4; ++r) {
    float bb = bias[m0 + ti*4 + r];
    float4 o4 = make_float4(acc[r][0]+bb, acc[r][1]+bb, acc[r][2]+bb, acc[r][3]+bb);
    *(float4*)&Ob[(long)(m0+ti*4+r)*N + n0 + tj*4] = o4;
  }
}

// ---------------- flash-style axial attention, fp32, L=2048, d=64 ------------
// qkv layout: [2*B][768][L]; op layout: [2*B][256][L]
__global__ __launch_bounds__(256) void attn_kernel(const float* __restrict__ qkv,
                                                   float* __restrict__ op) {
  int inst = blockIdx.y;                         // 0..31
  int hh = inst & 3, bb = (inst >> 2) & 3, br = inst >> 4;
  const float* base = qkv + (long)(br*B_ + bb) * 3 * C_ * L_;
  const float* Qg = base + (long)(hh*DH_) * L_;
  const float* Kg = base + (long)(C_   + hh*DH_) * L_;
  const float* Vg = base + (long)(2*C_ + hh*DH_) * L_;
  float* Og = op + (long)((br*B_ + bb)*C_ + hh*DH_) * L_;
  int q0 = blockIdx.x * 64;

  __shared__ float Qs[64][68];
  __shared__ float KPs[64][68];   // K tile, reused as P tile
  __shared__ float Vs[64][68];

  int tid = threadIdx.x;
  int ti = tid >> 4, tj = tid & 15;

  for (int idx = tid; idx < 64*64; idx += 256) {
    int c = idx >> 6, i = idx & 63;
    Qs[c][i] = Qg[(long)c*L_ + q0 + i];
  }

  float m_run[4], l_run[4], acc[4][4];
  #pragma unroll
  for (int r = 0; r < 4; ++r) {
    m_run[r] = -1e30f; l_run[r] = 0.f;
    #pragma unroll
    for (int s = 0; s < 4; ++s) acc[r][s] = 0.f;
  }
  const float scl = 0.0625f;   // 1/sqrt(256)

  for (int j0 = 0; j0 < L_; j0 += 64) {
    __syncthreads();                    // also orders initial Qs fill
    for (int idx = tid; idx < 64*64; idx += 256) {
      int c = idx >> 6, j = idx & 63;
      KPs[c][j] = Kg[(long)c*L_ + j0 + j];
      Vs[c][j]  = Vg[(long)c*L_ + j0 + j];
    }
    __syncthreads();
    // S tile: rows i = ti*4+r, cols j = tj*4+s
    float sv[4][4] = {{0.f}};
    #pragma unroll 8
    for (int c = 0; c < 64; ++c) {
      float4 a4 = *(const float4*)&Qs[c][ti*4];
      float4 b4 = *(const float4*)&KPs[c][tj*4];
      float av[4] = {a4.x, a4.y, a4.z, a4.w};
      float bv[4] = {b4.x, b4.y, b4.z, b4.w};
      #pragma unroll
      for (int r = 0; r < 4; ++r)
        #pragma unroll
        for (int s = 0; s < 4; ++s) sv[r][s] += av[r]*bv[s];
    }
    // online softmax (row reduce across the 16 tj lanes)
    float pv[4][4];
    #pragma unroll
    for (int r = 0; r < 4; ++r) {
      float mx = fmaxf(fmaxf(sv[r][0], sv[r][1]), fmaxf(sv[r][2], sv[r][3])) * scl;
      #pragma unroll
      for (int off = 1; off < 16; off <<= 1) mx = fmaxf(mx, __shfl_xor(mx, off));
      float m_new = fmaxf(m_run[r], mx);
      float fr = __expf(m_run[r] - m_new);
      float rs = 0.f;
      #pragma unroll
      for (int s = 0; s < 4; ++s) {
        pv[r][s] = __expf(sv[r][s]*scl - m_new);
        rs += pv[r][s];
      }
      #pragma unroll
      for (int off = 1; off < 16; off <<= 1) rs += __shfl_xor(rs, off);
      l_run[r] = l_run[r]*fr + rs;
      m_run[r] = m_new;
      #pragma unroll
      for (int s = 0; s < 4; ++s) acc[r][s] *= fr;
    }
    __syncthreads();                    // everyone done reading K from KPs
    #pragma unroll
    for (int r = 0; r < 4; ++r)
      *(float4*)&KPs[ti*4+r][tj*4] = make_float4(pv[r][0], pv[r][1], pv[r][2], pv[r][3]);
    __syncthreads();
    // PV: acc[r][s] += sum_j P[i_r][j] * V[c_s][j], c_s = tj*4+s
    #pragma unroll 8
    for (int j = 0; j < 64; ++j) {
      float pr[4], vv[4];
      #pragma unroll
      for (int r = 0; r < 4; ++r) pr[r] = KPs[ti*4+r][j];
      #pragma unroll
      for (int s = 0; s < 4; ++s) vv[s] = Vs[tj*4+s][j];
      #pragma unroll
      for (int r = 0; r < 4; ++r)
        #pragma unroll
        for (int s = 0; s < 4; ++s) acc[r][s] += pr[r]*vv[s];
    }
  }
  #pragma unroll
  for (int r = 0; r < 4; ++r) {
    float invl = 1.f / l_run[r];
    #pragma unroll
    for (int s = 0; s < 4; ++s)
      Og[(long)(tj*4+s)*L_ + q0 + ti*4 + r] = acc[r][s] * invl;
  }
}

// ------- fused: bilinear upsample (x8) both branches + add + dw3x3 + bias ----
// op layout: [2][B*C][L]; output z: (B,C,128,128)
// One block = one 32-row x 128-col tile of one (b,c) plane.
__global__ __launch_bounds__(256) void up_dwconv_kernel(const float* __restrict__ op,
    const float* __restrict__ w_dw, const float* __restrict__ b_dw,
    float* __restrict__ z) {
  int tile = blockIdx.x & 3;          // 4 row-tiles of 32
  long bc  = blockIdx.x >> 2;
  int c    = (int)(bc & (C_-1));
  int h0   = tile * 32;
  const float* oh = op + bc * L_;                    // (16,128)
  const float* ow = op + (long)B_*C_*L_ + bc * L_;   // (128,16)

  __shared__ float ohs[16*128];       // 8 KiB  — whole H-branch plane
  __shared__ float ows[34*16];        // 2.2 KiB — W-branch rows h0-1 .. h0+32
  __shared__ float ys[34][128];       // 17 KiB — y tile with vertical halo

  int tid = threadIdx.x;
  for (int i = tid; i < 16*128; i += 256) ohs[i] = oh[i];
  for (int i = tid; i < 34*16; i += 256) {
    int r = i >> 4, ww = i & 15;
    int hr = h0 - 1 + r;
    hr = max(0, min(H_-1, hr));       // clamped read; unused if out-of-plane
    ows[i] = ow[hr*16 + ww];
  }
  __syncthreads();

  // compute y rows h0-1 .. h0+32 (34 rows x 128 cols)
  for (int i = tid; i < 34*128; i += 256) {
    int r = i >> 7, w = i & 127;
    int h = h0 - 1 + r;
    float v = 0.f;
    if ((unsigned)h < (unsigned)H_) {
      float sh = fminf(fmaxf((h + 0.5f)*0.125f - 0.5f, 0.f), 15.f);
      int ih0 = (int)sh; int ih1 = min(ih0+1, 15); float fh = sh - (float)ih0;
      float vh = ohs[ih0*128 + w]*(1.f-fh) + ohs[ih1*128 + w]*fh;
      float sw = fminf(fmaxf((w + 0.5f)*0.125f - 0.5f, 0.f), 15.f);
      int iw0 = (int)sw; int iw1 = min(iw0+1, 15); float fw = sw - (float)iw0;
      const float* owr = ows + r*16;
      float vw = owr[iw0]*(1.f-fw) + owr[iw1]*fw;
      v = vh + vw;
    }
    ys[r][w] = v;                     // zero for out-of-plane halo rows
  }
  __syncthreads();

  // depthwise 3x3 on the tile (32 x 128 outputs, 16 per thread)
  float w00 = w_dw[c*9+0], w01 = w_dw[c*9+1], w02 = w_dw[c*9+2];
  float w10 = w_dw[c*9+3], w11 = w_dw[c*9+4], w12 = w_dw[c*9+5];
  float w20 = w_dw[c*9+6], w21 = w_dw[c*9+7], w22 = w_dw[c*9+8];
  float bb = b_dw[c];
  float* zp = z + bc * (H_*W_) + h0 * W_;
  for (int i = tid; i < 32*128; i += 256) {
    int hl = i >> 7, w = i & 127;
    int r = hl + 1;                   // center row in ys
    float s = bb;
    s += ys[r-1][w]*w01 + ys[r][w]*w11 + ys[r+1][w]*w21;
    if (w > 0)      s += ys[r-1][w-1]*w00 + ys[r][w-1]*w10 + ys[r+1][w-1]*w20;
    if (w < W_-1)   s += ys[r-1][w+1]*w02 + ys[r][w+1]*w12 + ys[r+1][w+1]*w22;
    zp[i] = s;
  }
}

extern "C" void kernel_launch(void* const* d_in, const int* in_sizes, int n_in,
                              void* d_out, int out_size, void* d_ws, size_t ws_size,
                              hipStream_t stream) {
  const float* x      = (const float*)d_in[0];
  const float* w_qkv  = (const float*)d_in[1];
  const float* b_qkv  = (const float*)d_in[2];
  const float* w_dw   = (const float*)d_in[3];
  const float* b_dw   = (const float*)d_in[4];
  const float* w_proj = (const float*)d_in[5];
  const float* b_proj = (const float*)d_in[6];
  float* out = (float*)d_out;
  float* ws  = (float*)d_ws;

  // workspace layout (floats):
  //  xp  [0,           4,194,304)   2*B*C*L    (dead after qkv gemm)
  //  qkv [4,194,304,  16,777,216)   2*B*768*L  (dead after attention)
  //  op  [16,777,216, 20,971,520)   2*B*C*L
  //  z = reuses [0, 16,777,216)     B*C*H*W    (xp+qkv region, exact fit)
  // total: 20,971,520 floats = 80 MiB
  float* xp  = ws;
  float* qkv = xp + (long)2*B_*C_*L_;
  float* op  = qkv + (long)2*B_*3*C_*L_;
  float* z   = ws;

  // 1) pool x -> xh, xw
  pool_kernel<<<dim3(B_*C_*2), 256, 0, stream>>>(x, xp);
  // 2) qkv on pooled tensors: 8 batches (2 branches x 4), M=768,N=2048,K=256
  gemm_bias_kernel<<<dim3(L_/64, 768/64, 2*B_), 256, 0, stream>>>(
      w_qkv, xp, b_qkv, qkv, 768, L_, C_, (long)C_*L_, (long)3*C_*L_);
  // 3) attention: 32 instances x 32 q-tiles
  attn_kernel<<<dim3(L_/64, 2*B_*HEADS_), 256, 0, stream>>>(qkv, op);
  // 4) fused upsample+add+dwconv: 4 tiles per (b,c) plane
  up_dwconv_kernel<<<dim3(B_*C_*4), 256, 0, stream>>>(op, w_dw, b_dw, z);
  // 5) 1x1 projection: per-batch M=256,N=16384,K=256
  gemm_bias_kernel<<<dim3(H_*W_/64, C_/64, B_), 256, 0, stream>>>(
      w_proj, z, b_proj, out, C_, H_*W_, C_, (long)C_*H_*W_, (long)C_*H_*W_);
}

// Round 4
// 545.814 us; speedup vs baseline: 1.8361x; 1.8361x over previous
//
#include <hip/hip_runtime.h>

#define B_ 4
#define C_ 256
#define H_ 128
#define W_ 128
#define HEADS_ 4
#define DH_ 64
#define L_ 2048                    // pooled sequence length 16*128 = 128*16
#define NPIX_ ((long)B_*C_*H_*W_)  // 16,777,216

typedef __attribute__((ext_vector_type(8))) short bf16x8;
typedef __attribute__((ext_vector_type(4))) short bf16x4;
typedef __attribute__((ext_vector_type(4))) float f32x4;

__device__ inline short f2bf(float f) {
  union { float f; unsigned u; } v; v.f = f;
  unsigned r = v.u + 0x7fff + ((v.u >> 16) & 1);   // RNE
  return (short)(r >> 16);
}

// ---------------- pool: x (B,C,128,128) -> xh (B,C,16,128), xw (B,C,128,16) --
// xp layout: [2][B*C][L]  (branch 0 = H-pooled, branch 1 = W-pooled)
__global__ __launch_bounds__(256) void pool_kernel(const float* __restrict__ x,
                                                   float* __restrict__ xp) {
  int part = blockIdx.x & 1;          // half-plane (64 rows)
  int bc   = blockIdx.x >> 1;
  const float* px = x + (long)bc * (H_*W_) + (long)part * 64 * W_;
  __shared__ float pl[64 * W_];       // 32 KiB
  for (int i = threadIdx.x; i < 64*W_; i += 256) pl[i] = px[i];
  __syncthreads();
  const float inv = 0.125f;
  float* xh = xp + (long)bc * L_ + (long)part * 8 * W_;
  for (int i = threadIdx.x; i < 8*W_; i += 256) {
    int hh = i >> 7, w = i & 127;
    float s = 0.f;
    #pragma unroll
    for (int p = 0; p < 8; ++p) s += pl[(hh*8+p)*W_ + w];
    xh[i] = s * inv;
  }
  float* xw = xp + (long)(B_*C_ + bc) * L_ + (long)part * 64 * 16;
  for (int i = threadIdx.x; i < 64*16; i += 256) {
    int h = i >> 4, ww = i & 15;
    float s = 0.f;
    #pragma unroll
    for (int p = 0; p < 8; ++p) s += pl[h*W_ + ww*8 + p];
    xw[i] = s * inv;
  }
}

// ---------------- generic tiled GEMM with bias: Out[z] = A(MxK) * X[z](KxN) + b
__global__ __launch_bounds__(256) void gemm_bias_kernel(
    const float* __restrict__ A, const float* __restrict__ X,
    const float* __restrict__ bias, float* __restrict__ Out,
    int M, int N, int K, long xStride, long oStride) {
  const float* Xb = X + (long)blockIdx.z * xStride;
  float* Ob = Out + (long)blockIdx.z * oStride;
  int m0 = blockIdx.y * 64, n0 = blockIdx.x * 64;
  __shared__ float As[32][68];
  __shared__ float Xs[32][68];
  int tid = threadIdx.x;
  int ti = tid >> 4, tj = tid & 15;
  float acc[4][4] = {{0.f}};
  for (int k0 = 0; k0 < K; k0 += 32) {
    for (int idx = tid; idx < 64*32; idx += 256) {
      int o = idx >> 5, kk = idx & 31;
      As[kk][o] = A[(long)(m0+o)*K + k0 + kk];
    }
    for (int idx = tid; idx < 32*64; idx += 256) {
      int kk = idx >> 6, j = idx & 63;
      Xs[kk][j] = Xb[(long)(k0+kk)*N + n0 + j];
    }
    __syncthreads();
    #pragma unroll 8
    for (int kk = 0; kk < 32; ++kk) {
      float4 a4 = *(const float4*)&As[kk][ti*4];
      float4 b4 = *(const float4*)&Xs[kk][tj*4];
      float av[4] = {a4.x, a4.y, a4.z, a4.w};
      float bv[4] = {b4.x, b4.y, b4.z, b4.w};
      #pragma unroll
      for (int r = 0; r < 4; ++r)
        #pragma unroll
        for (int s = 0; s < 4; ++s) acc[r][s] += av[r]*bv[s];
    }
    __syncthreads();
  }
  #pragma unroll
  for (int r = 0; r < 4; ++r) {
    float bb = bias[m0 + ti*4 + r];
    float4 o4 = make_float4(acc[r][0]+bb, acc[r][1]+bb, acc[r][2]+bb, acc[r][3]+bb);
    *(float4*)&Ob[(long)(m0+ti*4+r)*N + n0 + tj*4] = o4;
  }
}

// ---------------- bf16-MFMA flash attention, L=2048, d=64 --------------------
// qkv layout: [2*B][768][L] fp32; op layout: [2*B][256][L] fp32
// Block: 256 thr = 4 waves; 128 q-rows/block (32/wave), j-tile 64.
#define LDQ 72                      // padded LDS row stride in shorts (144 B)
__global__ __launch_bounds__(256) void attn_mfma_kernel(const float* __restrict__ qkv,
                                                        float* __restrict__ op) {
  int inst = blockIdx.y;                         // 0..31
  int hh = inst & 3, bb = (inst >> 2) & 3, br = inst >> 4;
  const float* base = qkv + (long)(br*B_ + bb) * 3 * C_ * L_;
  const float* Qg = base + (long)(hh*DH_) * L_;
  const float* Kg = base + (long)(C_   + hh*DH_) * L_;
  const float* Vg = base + (long)(2*C_ + hh*DH_) * L_;
  float* Og = op + (long)((br*B_ + bb)*C_ + hh*DH_) * L_;
  int q0 = blockIdx.x * 128;

  // LDS carve: QsPs = Qs[128][LDQ] overlaid by Ps[4][32][LDQ] (same 9216 shorts)
  __shared__ __align__(16) short smem[9216 + 4608 + 4608];   // 36 KiB
  short* QsPs = smem;
  short* Ks   = smem + 9216;       // [64][LDQ]
  short* Vs   = smem + 9216 + 4608;// [64][LDQ]

  int tid = threadIdx.x;
  int l = tid & 63, w = tid >> 6;
  int lr = l & 15, lg = l >> 4;    // fragment row/col, k-group

  // ---- stage Q transposed: Qs[i][d] = Qg[d][q0+i] * 1/16, bf16
  #pragma unroll
  for (int it = 0; it < 8; ++it) {
    int d0 = (w << 2) + ((it & 3) << 4);
    int i  = l + ((it >> 2) << 6);
    bf16x4 t;
    #pragma unroll
    for (int e = 0; e < 4; ++e)
      t[e] = f2bf(Qg[(long)(d0+e)*L_ + q0 + i] * 0.0625f);
    *(bf16x4*)&QsPs[i*LDQ + d0] = t;
  }
  __syncthreads();

  // ---- hoist Q fragments (each wave owns rows w*32 .. w*32+31)
  bf16x8 qf[2][2];
  #pragma unroll
  for (int rt = 0; rt < 2; ++rt)
    #pragma unroll
    for (int ks = 0; ks < 2; ++ks)
      qf[rt][ks] = *(const bf16x8*)&QsPs[(w*32 + rt*16 + lr)*LDQ + ks*32 + lg*8];

  short* Pw = QsPs + w*32*LDQ;     // per-wave P block (aliases own Q rows)

  float m_run[8], l_run[8];
  f32x4 acc_o[2][4];
  #pragma unroll
  for (int s = 0; s < 8; ++s) { m_run[s] = -1e30f; l_run[s] = 0.f; }
  #pragma unroll
  for (int rt = 0; rt < 2; ++rt)
    #pragma unroll
    for (int dt = 0; dt < 4; ++dt) acc_o[rt][dt] = (f32x4)0.f;

  for (int j0 = 0; j0 < L_; j0 += 64) {
    __syncthreads();               // previous tile fully consumed
    // stage K transposed: Ks[j][d] = Kg[d][j0+j]
    #pragma unroll
    for (int it = 0; it < 4; ++it) {
      int d0 = (w << 2) + (it << 4);
      bf16x4 t;
      #pragma unroll
      for (int e = 0; e < 4; ++e)
        t[e] = f2bf(Kg[(long)(d0+e)*L_ + j0 + l]);
      *(bf16x4*)&Ks[l*LDQ + d0] = t;
    }
    // stage V direct: Vs[d][j] = Vg[d][j0+j]
    #pragma unroll
    for (int it = 0; it < 4; ++it) {
      int idx = tid + it*256;      // 1024 float4-quads
      int d = idx >> 4, jq = (idx & 15) << 2;
      float4 v4 = *(const float4*)&Vg[(long)d*L_ + j0 + jq];
      bf16x4 t;
      t[0] = f2bf(v4.x); t[1] = f2bf(v4.y); t[2] = f2bf(v4.z); t[3] = f2bf(v4.w);
      *(bf16x4*)&Vs[d*LDQ + jq] = t;
    }
    __syncthreads();

    // ---- S = Q·K^T  (rows: wave q-rows, cols: 64 j)
    f32x4 s_acc[2][4];
    #pragma unroll
    for (int rt = 0; rt < 2; ++rt)
      #pragma unroll
      for (int ct = 0; ct < 4; ++ct) s_acc[rt][ct] = (f32x4)0.f;
    #pragma unroll
    for (int ct = 0; ct < 4; ++ct) {
      bf16x8 kf0 = *(const bf16x8*)&Ks[(ct*16 + lr)*LDQ + lg*8];
      bf16x8 kf1 = *(const bf16x8*)&Ks[(ct*16 + lr)*LDQ + 32 + lg*8];
      #pragma unroll
      for (int rt = 0; rt < 2; ++rt) {
        s_acc[rt][ct] = __builtin_amdgcn_mfma_f32_16x16x32_bf16(qf[rt][0], kf0, s_acc[rt][ct], 0, 0, 0);
        s_acc[rt][ct] = __builtin_amdgcn_mfma_f32_16x16x32_bf16(qf[rt][1], kf1, s_acc[rt][ct], 0, 0, 0);
      }
    }

    // ---- online softmax (rows per lane: lg*4+r within each rt tile)
    #pragma unroll
    for (int rt = 0; rt < 2; ++rt) {
      #pragma unroll
      for (int r = 0; r < 4; ++r) {
        int sl = rt*4 + r;
        float mx = fmaxf(fmaxf(s_acc[rt][0][r], s_acc[rt][1][r]),
                         fmaxf(s_acc[rt][2][r], s_acc[rt][3][r]));
        #pragma unroll
        for (int off = 1; off < 16; off <<= 1) mx = fmaxf(mx, __shfl_xor(mx, off));
        float mn = fmaxf(m_run[sl], mx);
        float fr = __expf(m_run[sl] - mn);
        m_run[sl] = mn;
        float rs = 0.f;
        #pragma unroll
        for (int ct = 0; ct < 4; ++ct) {
          float p = __expf(s_acc[rt][ct][r] - mn);
          s_acc[rt][ct][r] = p;
          rs += p;
        }
        #pragma unroll
        for (int off = 1; off < 16; off <<= 1) rs += __shfl_xor(rs, off);
        l_run[sl] = l_run[sl]*fr + rs;
        #pragma unroll
        for (int dt = 0; dt < 4; ++dt) acc_o[rt][dt][r] *= fr;
      }
    }

    // ---- P -> LDS (bf16), own wave block only: no cross-wave barrier needed
    #pragma unroll
    for (int rt = 0; rt < 2; ++rt)
      #pragma unroll
      for (int ct = 0; ct < 4; ++ct)
        #pragma unroll
        for (int r = 0; r < 4; ++r)
          Pw[(rt*16 + lg*4 + r)*LDQ + ct*16 + lr] = f2bf(s_acc[rt][ct][r]);

    // ---- O += P·V
    #pragma unroll
    for (int ks = 0; ks < 2; ++ks) {
      bf16x8 pf[2];
      #pragma unroll
      for (int rt = 0; rt < 2; ++rt)
        pf[rt] = *(const bf16x8*)&Pw[(rt*16 + lr)*LDQ + ks*32 + lg*8];
      #pragma unroll
      for (int dt = 0; dt < 4; ++dt) {
        bf16x8 vf = *(const bf16x8*)&Vs[(dt*16 + lr)*LDQ + ks*32 + lg*8];
        #pragma unroll
        for (int rt = 0; rt < 2; ++rt)
          acc_o[rt][dt] = __builtin_amdgcn_mfma_f32_16x16x32_bf16(pf[rt], vf, acc_o[rt][dt], 0, 0, 0);
      }
    }
  }

  // ---- epilogue: normalize, write O (op[d'][i])
  #pragma unroll
  for (int rt = 0; rt < 2; ++rt)
    #pragma unroll
    for (int r = 0; r < 4; ++r) {
      float invl = 1.f / l_run[rt*4 + r];
      int i = q0 + w*32 + rt*16 + lg*4 + r;
      #pragma unroll
      for (int dt = 0; dt < 4; ++dt)
        Og[(long)(dt*16 + lr)*L_ + i] = acc_o[rt][dt][r] * invl;
    }
}

// ------- fused: bilinear upsample (x8) both branches + add + dw3x3 + bias ----
__global__ __launch_bounds__(256) void up_dwconv_kernel(const float* __restrict__ op,
    const float* __restrict__ w_dw, const float* __restrict__ b_dw,
    float* __restrict__ z) {
  int tile = blockIdx.x & 3;          // 4 row-tiles of 32
  long bc  = blockIdx.x >> 2;
  int c    = (int)(bc & (C_-1));
  int h0   = tile * 32;
  const float* oh = op + bc * L_;                    // (16,128)
  const float* ow = op + (long)B_*C_*L_ + bc * L_;   // (128,16)

  __shared__ float ohs[16*128];
  __shared__ float ows[34*16];
  __shared__ float ys[34][128];

  int tid = threadIdx.x;
  for (int i = tid; i < 16*128; i += 256) ohs[i] = oh[i];
  for (int i = tid; i < 34*16; i += 256) {
    int r = i >> 4, ww = i & 15;
    int hr = h0 - 1 + r;
    hr = max(0, min(H_-1, hr));
    ows[i] = ow[hr*16 + ww];
  }
  __syncthreads();

  for (int i = tid; i < 34*128; i += 256) {
    int r = i >> 7, w = i & 127;
    int h = h0 - 1 + r;
    float v = 0.f;
    if ((unsigned)h < (unsigned)H_) {
      float sh = fminf(fmaxf((h + 0.5f)*0.125f - 0.5f, 0.f), 15.f);
      int ih0 = (int)sh; int ih1 = min(ih0+1, 15); float fh = sh - (float)ih0;
      float vh = ohs[ih0*128 + w]*(1.f-fh) + ohs[ih1*128 + w]*fh;
      float sw = fminf(fmaxf((w + 0.5f)*0.125f - 0.5f, 0.f), 15.f);
      int iw0 = (int)sw; int iw1 = min(iw0+1, 15); float fw = sw - (float)iw0;
      const float* owr = ows + r*16;
      float vw = owr[iw0]*(1.f-fw) + owr[iw1]*fw;
      v = vh + vw;
    }
    ys[r][w] = v;
  }
  __syncthreads();

  float w00 = w_dw[c*9+0], w01 = w_dw[c*9+1], w02 = w_dw[c*9+2];
  float w10 = w_dw[c*9+3], w11 = w_dw[c*9+4], w12 = w_dw[c*9+5];
  float w20 = w_dw[c*9+6], w21 = w_dw[c*9+7], w22 = w_dw[c*9+8];
  float bb = b_dw[c];
  float* zp = z + bc * (H_*W_) + h0 * W_;
  for (int i = tid; i < 32*128; i += 256) {
    int hl = i >> 7, w = i & 127;
    int r = hl + 1;
    float s = bb;
    s += ys[r-1][w]*w01 + ys[r][w]*w11 + ys[r+1][w]*w21;
    if (w > 0)      s += ys[r-1][w-1]*w00 + ys[r][w-1]*w10 + ys[r+1][w-1]*w20;
    if (w < W_-1)   s += ys[r-1][w+1]*w02 + ys[r][w+1]*w12 + ys[r+1][w+1]*w22;
    zp[i] = s;
  }
}

extern "C" void kernel_launch(void* const* d_in, const int* in_sizes, int n_in,
                              void* d_out, int out_size, void* d_ws, size_t ws_size,
                              hipStream_t stream) {
  const float* x      = (const float*)d_in[0];
  const float* w_qkv  = (const float*)d_in[1];
  const float* b_qkv  = (const float*)d_in[2];
  const float* w_dw   = (const float*)d_in[3];
  const float* b_dw   = (const float*)d_in[4];
  const float* w_proj = (const float*)d_in[5];
  const float* b_proj = (const float*)d_in[6];
  float* out = (float*)d_out;
  float* ws  = (float*)d_ws;

  // workspace layout (floats):
  //  xp  [0,           4,194,304)   2*B*C*L    (dead after qkv gemm)
  //  qkv [4,194,304,  16,777,216)   2*B*768*L  (dead after attention)
  //  op  [16,777,216, 20,971,520)   2*B*C*L
  //  z = reuses [0, 16,777,216)     B*C*H*W    (exact fit)
  // total: 20,971,520 floats = 80 MiB
  float* xp  = ws;
  float* qkv = xp + (long)2*B_*C_*L_;
  float* op  = qkv + (long)2*B_*3*C_*L_;
  float* z   = ws;

  pool_kernel<<<dim3(B_*C_*2), 256, 0, stream>>>(x, xp);
  gemm_bias_kernel<<<dim3(L_/64, 768/64, 2*B_), 256, 0, stream>>>(
      w_qkv, xp, b_qkv, qkv, 768, L_, C_, (long)C_*L_, (long)3*C_*L_);
  attn_mfma_kernel<<<dim3(L_/128, 2*B_*HEADS_), 256, 0, stream>>>(qkv, op);
  up_dwconv_kernel<<<dim3(B_*C_*4), 256, 0, stream>>>(op, w_dw, b_dw, z);
  gemm_bias_kernel<<<dim3(H_*W_/64, C_/64, B_), 256, 0, stream>>>(
      w_proj, z, b_proj, out, C_, H_*W_, C_, (long)C_*H_*W_, (long)C_*H_*W_);
}

// Round 7
// 384.960 us; speedup vs baseline: 2.6033x; 1.4178x over previous
//
#include <hip/hip_runtime.h>

#define B_ 4
#define C_ 256
#define H_ 128
#define W_ 128
#define HEADS_ 4
#define DH_ 64
#define L_ 2048                    // pooled sequence length 16*128 = 128*16
#define NPIX_ ((long)B_*C_*H_*W_)  // 16,777,216

typedef __attribute__((ext_vector_type(8))) short bf16x8;
typedef __attribute__((ext_vector_type(4))) short bf16x4;
typedef __attribute__((ext_vector_type(4))) float f32x4;

__device__ inline short f2bf(float f) {
  union { float f; unsigned u; } v; v.f = f;
  unsigned r = v.u + 0x7fff + ((v.u >> 16) & 1);   // RNE
  return (short)(r >> 16);
}
__device__ inline float bf2f(short h) {
  union { unsigned u; float f; } v; v.u = ((unsigned)(unsigned short)h) << 16;
  return v.f;
}

// ---------------- pool: x (B,C,128,128) -> xh (B,C,16,128), xw (B,C,128,16) --
// xp layout: [2][B*C][L]  (branch 0 = H-pooled, branch 1 = W-pooled)
__global__ __launch_bounds__(256) void pool_kernel(const float* __restrict__ x,
                                                   float* __restrict__ xp) {
  int part = blockIdx.x & 1;          // half-plane (64 rows)
  int bc   = blockIdx.x >> 1;
  const float* px = x + (long)bc * (H_*W_) + (long)part * 64 * W_;
  __shared__ float pl[64 * W_];       // 32 KiB
  for (int i = threadIdx.x; i < 64*W_; i += 256) pl[i] = px[i];
  __syncthreads();
  const float inv = 0.125f;
  float* xh = xp + (long)bc * L_ + (long)part * 8 * W_;
  for (int i = threadIdx.x; i < 8*W_; i += 256) {
    int hh = i >> 7, w = i & 127;
    float s = 0.f;
    #pragma unroll
    for (int p = 0; p < 8; ++p) s += pl[(hh*8+p)*W_ + w];
    xh[i] = s * inv;
  }
  float* xw = xp + (long)(B_*C_ + bc) * L_ + (long)part * 64 * 16;
  for (int i = threadIdx.x; i < 64*16; i += 256) {
    int h = i >> 4, ww = i & 15;
    float s = 0.f;
    #pragma unroll
    for (int p = 0; p < 8; ++p) s += pl[h*W_ + ww*8 + p];
    xw[i] = s * inv;
  }
}

#define LDB_ 36   // LDS row stride (shorts) for GEMM tiles, 72 B

// -------- qkv GEMM, plain bf16 MFMA: Out = w_qkv(768x256) * xp[z](256x2048) + b
// Q rows (m<256) pre-scaled by 1/16. Outputs: qT,kT = [z][seq][256] bf16
// (transposed), vD = [z][256][seq] bf16 (direct).
__global__ __launch_bounds__(256) void gemm_qkv_mfma(
    const float* __restrict__ A, const float* __restrict__ X,
    const float* __restrict__ bias, short* __restrict__ qT,
    short* __restrict__ kT, short* __restrict__ vD) {
  int z = blockIdx.z;
  const float* Xb = X + (long)z * (C_*L_);
  int m0 = blockIdx.y * 64, n0 = blockIdx.x * 64;
  int seg = m0 >> 8;                 // 0=Q, 1=K, 2=V
  float ascale = (seg == 0) ? 0.0625f : 1.0f;
  __shared__ __align__(16) short As[64*LDB_];
  __shared__ __align__(16) short Xs[64*LDB_];
  int tid = threadIdx.x;
  int l = tid & 63, w = tid >> 6;
  int lr = l & 15, lg = l >> 4;
  f32x4 acc[4];
  #pragma unroll
  for (int nt = 0; nt < 4; ++nt) acc[nt] = (f32x4)0.f;

  for (int k0 = 0; k0 < C_; k0 += 32) {
    __syncthreads();
    {                                  // A tile: As[m][k] (row-major copy)
      int m = tid >> 2, sg = tid & 3;
      const float* ap = A + (long)(m0+m)*C_ + k0 + sg*8;
      bf16x8 t;
      #pragma unroll
      for (int e = 0; e < 8; ++e) t[e] = f2bf(ap[e] * ascale);
      *(bf16x8*)&As[m*LDB_ + sg*8] = t;
    }
    {                                  // X tile transposed: Xs[n][k]
      int n = tid & 63, kg = tid >> 6;
      bf16x8 t;
      #pragma unroll
      for (int e = 0; e < 8; ++e) t[e] = f2bf(Xb[(long)(k0+kg*8+e)*L_ + n0 + n]);
      *(bf16x8*)&Xs[n*LDB_ + kg*8] = t;
    }
    __syncthreads();
    bf16x8 af = *(const bf16x8*)&As[(w*16+lr)*LDB_ + lg*8];
    #pragma unroll
    for (int nt = 0; nt < 4; ++nt) {
      bf16x8 xf = *(const bf16x8*)&Xs[(nt*16+lr)*LDB_ + lg*8];
      acc[nt] = __builtin_amdgcn_mfma_f32_16x16x32_bf16(af, xf, acc[nt], 0, 0, 0);
    }
  }

  int mloc = (m0 & 255) + w*16 + lg*4;   // row within segment
  #pragma unroll
  for (int nt = 0; nt < 4; ++nt) {
    int n = n0 + nt*16 + lr;
    if (seg < 2) {                       // Q/K: transposed bf16 [seq][256]
      short* dst = (seg == 0 ? qT : kT) + ((long)z*L_ + n)*C_ + mloc;
      bf16x4 t;
      #pragma unroll
      for (int r = 0; r < 4; ++r)
        t[r] = f2bf(acc[nt][r] + bias[m0 + w*16 + lg*4 + r] * ascale);
      *(bf16x4*)dst = t;
    } else {                             // V: direct bf16 [256][seq]
      #pragma unroll
      for (int r = 0; r < 4; ++r)
        vD[((long)z*C_ + mloc + r)*L_ + n] =
            f2bf(acc[nt][r] + bias[m0 + w*16 + lg*4 + r]);
    }
  }
}

// -------- proj GEMM, split-bf16 (hi+lo) MFMA: out = w_proj(256x256)*z(256x16384)+b
__global__ __launch_bounds__(256) void gemm_proj_mfma(
    const float* __restrict__ A, const float* __restrict__ X,
    const float* __restrict__ bias, float* __restrict__ Out) {
  const int N = H_*W_;
  int z = blockIdx.z;
  const float* Xb = X + (long)z * (C_*N);
  float* Ob = Out + (long)z * (C_*N);
  int m0 = blockIdx.y * 64, n0 = blockIdx.x * 64;
  __shared__ __align__(16) short Ash[64*LDB_], Asl[64*LDB_];
  __shared__ __align__(16) short Xsh[64*LDB_], Xsl[64*LDB_];
  int tid = threadIdx.x;
  int l = tid & 63, w = tid >> 6;
  int lr = l & 15, lg = l >> 4;
  f32x4 acc[4];
  #pragma unroll
  for (int nt = 0; nt < 4; ++nt) acc[nt] = (f32x4)0.f;

  for (int k0 = 0; k0 < C_; k0 += 32) {
    __syncthreads();
    {
      int m = tid >> 2, sg = tid & 3;
      const float* ap = A + (long)(m0+m)*C_ + k0 + sg*8;
      bf16x8 th, tl;
      #pragma unroll
      for (int e = 0; e < 8; ++e) {
        float a = ap[e];
        short h = f2bf(a);
        th[e] = h; tl[e] = f2bf(a - bf2f(h));
      }
      *(bf16x8*)&Ash[m*LDB_ + sg*8] = th;
      *(bf16x8*)&Asl[m*LDB_ + sg*8] = tl;
    }
    {
      int n = tid & 63, kg = tid >> 6;
      bf16x8 th, tl;
      #pragma unroll
      for (int e = 0; e < 8; ++e) {
        float a = Xb[(long)(k0+kg*8+e)*N + n0 + n];
        short h = f2bf(a);
        th[e] = h; tl[e] = f2bf(a - bf2f(h));
      }
      *(bf16x8*)&Xsh[n*LDB_ + kg*8] = th;
      *(bf16x8*)&Xsl[n*LDB_ + kg*8] = tl;
    }
    __syncthreads();
    bf16x8 ah = *(const bf16x8*)&Ash[(w*16+lr)*LDB_ + lg*8];
    bf16x8 al = *(const bf16x8*)&Asl[(w*16+lr)*LDB_ + lg*8];
    #pragma unroll
    for (int nt = 0; nt < 4; ++nt) {
      bf16x8 xh = *(const bf16x8*)&Xsh[(nt*16+lr)*LDB_ + lg*8];
      bf16x8 xl = *(const bf16x8*)&Xsl[(nt*16+lr)*LDB_ + lg*8];
      acc[nt] = __builtin_amdgcn_mfma_f32_16x16x32_bf16(ah, xh, acc[nt], 0, 0, 0);
      acc[nt] = __builtin_amdgcn_mfma_f32_16x16x32_bf16(ah, xl, acc[nt], 0, 0, 0);
      acc[nt] = __builtin_amdgcn_mfma_f32_16x16x32_bf16(al, xh, acc[nt], 0, 0, 0);
    }
  }
  #pragma unroll
  for (int nt = 0; nt < 4; ++nt) {
    #pragma unroll
    for (int r = 0; r < 4; ++r) {
      int m = m0 + w*16 + lg*4 + r;
      Ob[(long)m*N + n0 + nt*16 + lr] = acc[nt][r] + bias[m];
    }
  }
}

// ---------------- bf16-MFMA flash attention, L=2048, d=64 --------------------
// qT,kT: [2*B][L][256] bf16 (Q pre-scaled by 1/16); vD: [2*B][256][L] bf16.
// op layout: [2*B][256][L] fp32. Block: 4 waves; 128 q-rows, j-tile 64.
#define LDQ 72                      // padded LDS row stride in shorts (144 B)
__global__ __launch_bounds__(256) void attn_mfma_kernel(
    const short* __restrict__ qT, const short* __restrict__ kT,
    const short* __restrict__ vD, float* __restrict__ op) {
  int inst = blockIdx.y;                         // 0..31
  int hh = inst & 3, zz = inst >> 2;             // head, branch-batch
  const short* Qg = qT + (long)zz * L_ * C_ + hh*DH_;
  const short* Kg = kT + (long)zz * L_ * C_ + hh*DH_;
  const short* Vg = vD + ((long)zz * C_ + hh*DH_) * L_;
  float* Og = op + (long)(zz*C_ + hh*DH_) * L_;
  int q0 = blockIdx.x * 128;

  // LDS carve: QsPs = Qs[128][LDQ] overlaid by Ps[4][32][LDQ]
  __shared__ __align__(16) short smem[9216 + 4608 + 4608];   // 36 KiB
  short* QsPs = smem;
  short* Ks   = smem + 9216;       // [64][LDQ]
  short* Vs   = smem + 9216 + 4608;// [64][LDQ]

  int tid = threadIdx.x;
  int l = tid & 63, w = tid >> 6;
  int lr = l & 15, lg = l >> 4;    // fragment row, k-group

  // ---- stage Q: direct row copies (already scaled, bf16)
  #pragma unroll
  for (int it = 0; it < 4; ++it) {
    int idx = tid + it*256;        // 1024 bf16x8 chunks
    int i = idx >> 3, ds = (idx & 7) << 3;
    *(bf16x8*)&QsPs[i*LDQ + ds] = *(const bf16x8*)&Qg[(long)(q0+i)*C_ + ds];
  }
  __syncthreads();

  // ---- hoist Q fragments (each wave owns rows w*32 .. w*32+31)
  bf16x8 qf[2][2];
  #pragma unroll
  for (int rt = 0; rt < 2; ++rt)
    #pragma unroll
    for (int ks = 0; ks < 2; ++ks)
      qf[rt][ks] = *(const bf16x8*)&QsPs[(w*32 + rt*16 + lr)*LDQ + ks*32 + lg*8];

  short* Pw = QsPs + w*32*LDQ;     // per-wave P block (aliases own Q rows)

  float m_run[8], l_run[8];
  f32x4 acc_o[2][4];
  #pragma unroll
  for (int s = 0; s < 8; ++s) { m_run[s] = -1e30f; l_run[s] = 0.f; }
  #pragma unroll
  for (int rt = 0; rt < 2; ++rt)
    #pragma unroll
    for (int dt = 0; dt < 4; ++dt) acc_o[rt][dt] = (f32x4)0.f;

  for (int j0 = 0; j0 < L_; j0 += 64) {
    __syncthreads();               // previous tile fully consumed
    #pragma unroll
    for (int it = 0; it < 2; ++it) {   // K rows: Ks[j][d]
      int idx = tid + it*256;          // 512 chunks
      int j = idx >> 3, ds = (idx & 7) << 3;
      *(bf16x8*)&Ks[j*LDQ + ds] = *(const bf16x8*)&Kg[(long)(j0+j)*C_ + ds];
    }
    #pragma unroll
    for (int it = 0; it < 2; ++it) {   // V rows: Vs[d][j]
      int idx = tid + it*256;
      int d = idx >> 3, js = (idx & 7) << 3;
      *(bf16x8*)&Vs[d*LDQ + js] = *(const bf16x8*)&Vg[(long)d*L_ + j0 + js];
    }
    __syncthreads();

    // ---- S = Q·K^T
    f32x4 s_acc[2][4];
    #pragma unroll
    for (int rt = 0; rt < 2; ++rt)
      #pragma unroll
      for (int ct = 0; ct < 4; ++ct) s_acc[rt][ct] = (f32x4)0.f;
    #pragma unroll
    for (int ct = 0; ct < 4; ++ct) {
      bf16x8 kf0 = *(const bf16x8*)&Ks[(ct*16 + lr)*LDQ + lg*8];
      bf16x8 kf1 = *(const bf16x8*)&Ks[(ct*16 + lr)*LDQ + 32 + lg*8];
      #pragma unroll
      for (int rt = 0; rt < 2; ++rt) {
        s_acc[rt][ct] = __builtin_amdgcn_mfma_f32_16x16x32_bf16(qf[rt][0], kf0, s_acc[rt][ct], 0, 0, 0);
        s_acc[rt][ct] = __builtin_amdgcn_mfma_f32_16x16x32_bf16(qf[rt][1], kf1, s_acc[rt][ct], 0, 0, 0);
      }
    }

    // ---- online softmax (rows per lane: lg*4+r within each rt tile)
    #pragma unroll
    for (int rt = 0; rt < 2; ++rt) {
      #pragma unroll
      for (int r = 0; r < 4; ++r) {
        int sl = rt*4 + r;
        float mx = fmaxf(fmaxf(s_acc[rt][0][r], s_acc[rt][1][r]),
                         fmaxf(s_acc[rt][2][r], s_acc[rt][3][r]));
        #pragma unroll
        for (int off = 1; off < 16; off <<= 1) mx = fmaxf(mx, __shfl_xor(mx, off));
        float mn = fmaxf(m_run[sl], mx);
        float fr = __expf(m_run[sl] - mn);
        m_run[sl] = mn;
        float rs = 0.f;
        #pragma unroll
        for (int ct = 0; ct < 4; ++ct) {
          float p = __expf(s_acc[rt][ct][r] - mn);
          s_acc[rt][ct][r] = p;
          rs += p;
        }
        #pragma unroll
        for (int off = 1; off < 16; off <<= 1) rs += __shfl_xor(rs, off);
        l_run[sl] = l_run[sl]*fr + rs;
        #pragma unroll
        for (int dt = 0; dt < 4; ++dt) acc_o[rt][dt][r] *= fr;
      }
    }

    // ---- P -> LDS (bf16), own wave block only
    #pragma unroll
    for (int rt = 0; rt < 2; ++rt)
      #pragma unroll
      for (int ct = 0; ct < 4; ++ct)
        #pragma unroll
        for (int r = 0; r < 4; ++r)
          Pw[(rt*16 + lg*4 + r)*LDQ + ct*16 + lr] = f2bf(s_acc[rt][ct][r]);

    // ---- O += P·V
    #pragma unroll
    for (int ks = 0; ks < 2; ++ks) {
      bf16x8 pf[2];
      #pragma unroll
      for (int rt = 0; rt < 2; ++rt)
        pf[rt] = *(const bf16x8*)&Pw[(rt*16 + lr)*LDQ + ks*32 + lg*8];
      #pragma unroll
      for (int dt = 0; dt < 4; ++dt) {
        bf16x8 vf = *(const bf16x8*)&Vs[(dt*16 + lr)*LDQ + ks*32 + lg*8];
        #pragma unroll
        for (int rt = 0; rt < 2; ++rt)
          acc_o[rt][dt] = __builtin_amdgcn_mfma_f32_16x16x32_bf16(pf[rt], vf, acc_o[rt][dt], 0, 0, 0);
      }
    }
  }

  // ---- epilogue: normalize, write O (op[d'][i])
  #pragma unroll
  for (int rt = 0; rt < 2; ++rt)
    #pragma unroll
    for (int r = 0; r < 4; ++r) {
      float invl = 1.f / l_run[rt*4 + r];
      int i = q0 + w*32 + rt*16 + lg*4 + r;
      #pragma unroll
      for (int dt = 0; dt < 4; ++dt)
        Og[(long)(dt*16 + lr)*L_ + i] = acc_o[rt][dt][r] * invl;
    }
}

// ------- fused: bilinear upsample (x8) both branches + add + dw3x3 + bias ----
__global__ __launch_bounds__(256) void up_dwconv_kernel(const float* __restrict__ op,
    const float* __restrict__ w_dw, const float* __restrict__ b_dw,
    float* __restrict__ z) {
  int tile = blockIdx.x & 3;          // 4 row-tiles of 32
  long bc  = blockIdx.x >> 2;
  int c    = (int)(bc & (C_-1));
  int h0   = tile * 32;
  const float* oh = op + bc * L_;                    // (16,128)
  const float* ow = op + (long)B_*C_*L_ + bc * L_;   // (128,16)

  __shared__ float ohs[16*128];
  __shared__ float ows[34*16];
  __shared__ float ys[34][128];

  int tid = threadIdx.x;
  for (int i = tid; i < 16*128; i += 256) ohs[i] = oh[i];
  for (int i = tid; i < 34*16; i += 256) {
    int r = i >> 4, ww = i & 15;
    int hr = h0 - 1 + r;
    hr = max(0, min(H_-1, hr));
    ows[i] = ow[hr*16 + ww];
  }
  __syncthreads();

  for (int i = tid; i < 34*128; i += 256) {
    int r = i >> 7, w = i & 127;
    int h = h0 - 1 + r;
    float v = 0.f;
    if ((unsigned)h < (unsigned)H_) {
      float sh = fminf(fmaxf((h + 0.5f)*0.125f - 0.5f, 0.f), 15.f);
      int ih0 = (int)sh; int ih1 = min(ih0+1, 15); float fh = sh - (float)ih0;
      float vh = ohs[ih0*128 + w]*(1.f-fh) + ohs[ih1*128 + w]*fh;
      float sw = fminf(fmaxf((w + 0.5f)*0.125f - 0.5f, 0.f), 15.f);
      int iw0 = (int)sw; int iw1 = min(iw0+1, 15); float fw = sw - (float)iw0;
      const float* owr = ows + r*16;
      float vw = owr[iw0]*(1.f-fw) + owr[iw1]*fw;
      v = vh + vw;
    }
    ys[r][w] = v;
  }
  __syncthreads();

  float w00 = w_dw[c*9+0], w01 = w_dw[c*9+1], w02 = w_dw[c*9+2];
  float w10 = w_dw[c*9+3], w11 = w_dw[c*9+4], w12 = w_dw[c*9+5];
  float w20 = w_dw[c*9+6], w21 = w_dw[c*9+7], w22 = w_dw[c*9+8];
  float bb = b_dw[c];
  float* zp = z + bc * (H_*W_) + h0 * W_;
  for (int i = tid; i < 32*128; i += 256) {
    int hl = i >> 7, w = i & 127;
    int r = hl + 1;
    float s = bb;
    s += ys[r-1][w]*w01 + ys[r][w]*w11 + ys[r+1][w]*w21;
    if (w > 0)      s += ys[r-1][w-1]*w00 + ys[r][w-1]*w10 + ys[r+1][w-1]*w20;
    if (w < W_-1)   s += ys[r-1][w+1]*w02 + ys[r][w+1]*w12 + ys[r+1][w+1]*w22;
    zp[i] = s;
  }
}

extern "C" void kernel_launch(void* const* d_in, const int* in_sizes, int n_in,
                              void* d_out, int out_size, void* d_ws, size_t ws_size,
                              hipStream_t stream) {
  const float* x      = (const float*)d_in[0];
  const float* w_qkv  = (const float*)d_in[1];
  const float* b_qkv  = (const float*)d_in[2];
  const float* w_dw   = (const float*)d_in[3];
  const float* b_dw   = (const float*)d_in[4];
  const float* w_proj = (const float*)d_in[5];
  const float* b_proj = (const float*)d_in[6];
  float* out = (float*)d_out;
  float* ws  = (float*)d_ws;

  // workspace layout (float units, 80 MiB total — same footprint that passed):
  //  xp   [0,          4,194,304)  2*B*C*L fp32            (dead after qkv gemm)
  //  qkvb [4,194,304, 10,485,760)  3 x 8 x 2048 x 256 bf16 (dead after attn)
  //  op   [16,777,216, 20,971,520) 2*B*C*L fp32
  //  z    [0,         16,777,216)  B*C*H*W fp32 (overlays xp+qkvb after attn)
  float* xp  = ws;
  short* qT  = (short*)(ws + (long)4194304);
  short* kT  = qT + (long)2*B_*L_*C_;
  short* vD  = kT + (long)2*B_*L_*C_;
  float* op  = ws + (long)16777216;
  float* z   = ws;

  // 1) pool x -> xh, xw
  pool_kernel<<<dim3(B_*C_*2), 256, 0, stream>>>(x, xp);
  // 2) qkv bf16 MFMA GEMM: 8 batches, M=768, N=2048, K=256
  gemm_qkv_mfma<<<dim3(L_/64, 768/64, 2*B_), 256, 0, stream>>>(
      w_qkv, xp, b_qkv, qT, kT, vD);
  // 3) attention: 16 q-tiles x 32 instances
  attn_mfma_kernel<<<dim3(L_/128, 2*B_*HEADS_), 256, 0, stream>>>(qT, kT, vD, op);
  // 4) fused upsample+add+dwconv
  up_dwconv_kernel<<<dim3(B_*C_*4), 256, 0, stream>>>(op, w_dw, b_dw, z);
  // 5) 1x1 projection, split-bf16 MFMA: M=256, N=16384, K=256
  gemm_proj_mfma<<<dim3(H_*W_/64, C_/64, B_), 256, 0, stream>>>(
      w_proj, z, b_proj, out);
}